// Round 13
// baseline (225.211 us; speedup 1.0000x reference)
//
#include <hip/hip_runtime.h>
#include <stdint.h>

// Fused attention: q/k/v projections + softmax(QK^T/32 + mask) @ V
// B=4, S=2048, E=1024.
// gemmF (QKV from raw f32): BK=64, NT=16, ring-3 LDS (48KB slots, 144KB),
// single staging reg set (1-iter lead; tile ~3000cyc > 900cyc HBM latency),
// one lgkmcnt(0)+barrier per tile, (row&7)<<4 swizzle for 128B rows.
// LDS slot reuse distance = 2 barriers (R9 ledger requirement).
// gemmJ (scores/PV) = R8-proven ring-4 BK=32 gload_lds structure.
// Softmax eliminated: scores epilogue computes E=exp(x/32+mask) (bounded
// ~e^6), writes E bf16 + atomic row sums; PV epilogue scales by 1/sRow.
//
// ws layout (MB offsets): [0,16) qb / [16,32) kb / [32,48) vT /
// [48,+32KB) sRow / [80,112) Sb=E.

typedef __attribute__((ext_vector_type(8))) short s8v;
typedef __attribute__((ext_vector_type(4))) float f32x4;
typedef __attribute__((ext_vector_type(4))) unsigned u32x4;

__device__ __forceinline__ unsigned short f2b(float f) {
  union { float f; unsigned u; } c; c.f = f;
  unsigned r = c.u + 0x7fffu + ((c.u >> 16) & 1u);   // RNE, no NaN inputs
  return (unsigned short)(r >> 16);
}

__device__ __forceinline__ void gload_lds16(const void* gsrc, void* ldst) {
  __builtin_amdgcn_global_load_lds(
      (__attribute__((address_space(1))) unsigned int*)(uintptr_t)gsrc,
      (__attribute__((address_space(3))) unsigned int*)(unsigned)(uintptr_t)ldst,
      16, 0, 0);
}

template <int N> __device__ __forceinline__ void waitvm() {
  if constexpr (N == 4)      asm volatile("s_waitcnt vmcnt(4)" ::: "memory");
  else if constexpr (N == 3) asm volatile("s_waitcnt vmcnt(3)" ::: "memory");
  else                       asm volatile("s_waitcnt vmcnt(0)" ::: "memory");
}

// ---------------- gemmF: QKV projection from f32 sources, BK=64 ---------
struct JobF {
  const float* A; const float* B; unsigned short* C; const float* bias;
  long sAb, sBb, sCb;
  int lda, ldb, ldc, tilesN, tilesMN, bmode;   // bias: 1=col, 2=row
};

// NT GEMM from f32: C[m][n] = bf16(sum_k A[m][k]B[n][k] + bias). 256x128
// tile, 8 waves (2Mx4N, per-wave 128x32), BK=64, K=1024 (16 tiles),
// reg-staged f32 + v_cvt_pk_bf16_f32 + ds_write, ring-3 LDS.
__global__ __launch_bounds__(512, 1) void gemmF(JobF j0, JobF j1, JobF j2,
                                                int b0, int b1) {
  constexpr int ASLOT = 256 * 128;      // bf16 bytes (256 rows x 128B)
  constexpr int SLOT = ASLOT + 128 * 128;
  constexpr int NT = 16;                // K=1024, BK=64
  __shared__ __align__(16) char lds[3 * SLOT];

  const int nwg = gridDim.x;
  const int hw = blockIdx.x;
  int g = (hw & 7) * (nwg >> 3) + (hw >> 3);
  const JobF J = (g < b0) ? j0 : (g < b1) ? j1 : j2;
  g -= (g < b0) ? 0 : (g < b1) ? b0 : b1;

  const int batch = g / J.tilesMN;
  const int tt = g - batch * J.tilesMN;
  const int tm = tt / J.tilesN, tn = tt - tm * J.tilesN;
  const int brow = tm << 8, bcol = tn << 7;

  const int tid = threadIdx.x, lane = tid & 63, w = tid >> 6;
  const int wm = w >> 2, wn = w & 3;
  const int fr = lane & 15, fq = lane >> 4;

  const float* Ab = J.A + (long)batch * J.sAb;
  const float* Bb = J.B + (long)batch * J.sBb;

  // 48 1KB-bf16 chunks/K-tile (A:0-31, B:32-47); wave w owns {w+8j, j<6}.
  // 128B rows; swizzle byte^=(row&7)<<4 (involution); source inverse-swz.
  const float* gsrcF[6];
  int ldsdst[6];
#pragma unroll
  for (int i = 0; i < 6; i++) {
    const int c = w + i * 8;
    const bool isA = (c < 32);
    const int cc = isA ? c : c - 32;
    const int roff = cc * 1024 + lane * 16;
    const int L = roff ^ (((roff >> 7) & 7) << 4);
    const int row = L >> 7, elem = (L & 127) >> 1;  // logical f32 elem
    gsrcF[i] = (isA ? (Ab + (long)(brow + row) * J.lda)
                    : (Bb + (long)(bcol + row) * J.ldb)) + elem;
    ldsdst[i] = (isA ? 0 : ASLOT) + cc * 1024 + lane * 16;
  }

  // ds_read offsets (ks=0; ^64 gives ks=1 — swizzle mask depends only on row)
  int offA[8], offB[2];
#pragma unroll
  for (int mi = 0; mi < 8; mi++) {
    const int rA = wm * 128 + mi * 16 + fr;
    offA[mi] = rA * 128 + ((fq * 16) ^ ((rA & 7) << 4));
  }
#pragma unroll
  for (int ni = 0; ni < 2; ni++) {
    const int rB = wn * 32 + ni * 16 + fr;
    offB[ni] = ASLOT + rB * 128 + ((fq * 16) ^ ((rB & 7) << 4));
  }

  f32x4 acc[8][2];
#pragma unroll
  for (int mi = 0; mi < 8; mi++)
#pragma unroll
    for (int ni = 0; ni < 2; ni++) acc[mi][ni] = (f32x4){0.f, 0.f, 0.f, 0.f};

  f32x4 sLo[6], sHi[6];                 // single staging set (48 VGPR)

#define ISSUE(kt) { \
  _Pragma("unroll") \
  for (int i_ = 0; i_ < 6; i_++) { \
    const float* p_ = gsrcF[i_] + (long)(kt) * 64; \
    sLo[i_] = *(const f32x4*)p_; sHi[i_] = *(const f32x4*)(p_ + 4); } }

#define CVTWRITE(sb_) { \
  _Pragma("unroll") \
  for (int i_ = 0; i_ < 6; i_++) { \
    unsigned o0_, o1_, o2_, o3_; \
    asm("v_cvt_pk_bf16_f32 %0, %1, %2" : "=v"(o0_) : "v"(sLo[i_][0]), "v"(sLo[i_][1])); \
    asm("v_cvt_pk_bf16_f32 %0, %1, %2" : "=v"(o1_) : "v"(sLo[i_][2]), "v"(sLo[i_][3])); \
    asm("v_cvt_pk_bf16_f32 %0, %1, %2" : "=v"(o2_) : "v"(sHi[i_][0]), "v"(sHi[i_][1])); \
    asm("v_cvt_pk_bf16_f32 %0, %1, %2" : "=v"(o3_) : "v"(sHi[i_][2]), "v"(sHi[i_][3])); \
    *(u32x4*)((sb_) + ldsdst[i_]) = (u32x4){o0_, o1_, o2_, o3_}; } }

#define MFMA_HALF(sb_, AM) { \
  s8v af_[4][2]; \
  _Pragma("unroll") \
  for (int mi_ = 0; mi_ < 4; mi_++) { \
    af_[mi_][0] = *(const s8v*)((sb_) + offA[(AM) + mi_]); \
    af_[mi_][1] = *(const s8v*)((sb_) + (offA[(AM) + mi_] ^ 64)); } \
  __builtin_amdgcn_s_setprio(1); \
  _Pragma("unroll") \
  for (int ks_ = 0; ks_ < 2; ks_++) \
    _Pragma("unroll") \
    for (int mi_ = 0; mi_ < 4; mi_++) \
      _Pragma("unroll") \
      for (int ni_ = 0; ni_ < 2; ni_++) \
        acc[(AM) + mi_][ni_] = __builtin_amdgcn_mfma_f32_16x16x32_bf16( \
            af_[mi_][ks_], bf_[ni_][ks_], acc[(AM) + mi_][ni_], 0, 0, 0); \
  __builtin_amdgcn_s_setprio(0); }

#define MFMA_BODY(sb_) { \
  s8v bf_[2][2]; \
  _Pragma("unroll") \
  for (int ni_ = 0; ni_ < 2; ni_++) { \
    bf_[ni_][0] = *(const s8v*)((sb_) + offB[ni_]); \
    bf_[ni_][1] = *(const s8v*)((sb_) + (offB[ni_] ^ 64)); } \
  MFMA_HALF(sb_, 0); \
  MFMA_HALF(sb_, 4); }

#define ENDBAR() { \
  asm volatile("s_waitcnt lgkmcnt(0)" ::: "memory"); \
  __builtin_amdgcn_s_barrier(); }

  // prologue: tile 0 -> slot 0 (vmcnt auto-waited by CVTWRITE deps);
  // tile 1's loads in flight; slot 0 published.
  ISSUE(0);
  CVTWRITE(lds);
  ISSUE(1);
  ENDBAR();

  // invariant at top of iter t: slot t%3 ready; staging set holds tile
  // t+1's f32 (in flight or landed); nothing else outstanding.
  int sCur = 0;
  for (int t = 0; t < NT; ++t) {
    const char* sb = lds + sCur * SLOT;
    int sNxt = sCur + 1; if (sNxt == 3) sNxt = 0;
    MFMA_BODY(sb);
    if (t + 1 < NT) {
      CVTWRITE(lds + sNxt * SLOT);      // consumes set (tile t+1)
      if (t + 2 < NT) ISSUE(t + 2);     // refill set
      ENDBAR();
    }
    sCur = sNxt;
  }

  // epilogue: C/D frag layout col=lane&15, row=(lane>>4)*4+r  [m89]
  const long cB = (long)batch * J.sCb;
#pragma unroll
  for (int mi = 0; mi < 8; mi++) {
    const int rbase = brow + wm * 128 + mi * 16 + fq * 4;
#pragma unroll
    for (int ni = 0; ni < 2; ni++) {
      const int col = bcol + wn * 32 + ni * 16 + fr;
      const float bc = (J.bmode == 1) ? J.bias[col] : 0.f;
#pragma unroll
      for (int r = 0; r < 4; r++) {
        const int row = rbase + r;
        float v = acc[mi][ni][r] + ((J.bmode == 2) ? J.bias[row] : bc);
        J.C[cB + (long)row * J.ldc + col] = f2b(v);
      }
    }
  }
#undef ISSUE
#undef CVTWRITE
#undef MFMA_HALF
#undef MFMA_BODY
#undef ENDBAR
}

// ---------------- gemmJ: bf16-source GEMM (scores / PV), R8-proven -------
struct Job {
  const unsigned short* A; const unsigned short* B; void* C;
  const float* bias; const float* mask; float* sRow;
  long sAb, sBb, sCb, sMb;
  int lda, ldb, ldc, ldM;
  int K, tilesN, tilesMN;
  float scale; int bmode;
};

// MODE 1: exp(.*scale+mask) -> bf16 out + atomic row sums (scores).
// MODE 2: f32 out * (1/sRow[row]) (PV with normalization).
template <int NFRAG, int MODE>
__global__ __launch_bounds__(512, 2) void gemmJ(Job j0, Job j1, Job j2,
                                                int b0, int b1) {
  constexpr int BN = NFRAG * 64;
  constexpr int ASLOT = 256 * 64;
  constexpr int BSLOT = BN * 64;
  constexpr int SLOT = ASLOT + BSLOT;
  constexpr int CH = SLOT / 1024;
  constexpr int GPW = CH / 8;
  static_assert(4 * SLOT <= 160 * 1024, "LDS budget");
  __shared__ __align__(16) char lds[4 * SLOT];   // ring-4: 2-barrier reuse

  const int nwg = gridDim.x;
  const int hw = blockIdx.x;
  int g = (hw & 7) * (nwg >> 3) + (hw >> 3);
  const Job J = (g < b0) ? j0 : (g < b1) ? j1 : j2;
  g -= (g < b0) ? 0 : (g < b1) ? b0 : b1;

  const int batch = g / J.tilesMN;
  const int tt = g - batch * J.tilesMN;
  const int tm = tt / J.tilesN, tn = tt - tm * J.tilesN;
  const int brow = tm << 8, bcol = tn * BN;

  const int tid = threadIdx.x;
  const int lane = tid & 63, w = tid >> 6;
  const int wm = w >> 2, wn = w & 3;
  const int fr = lane & 15, fq = lane >> 4;

  const unsigned short* Ab = J.A + (long)batch * J.sAb;
  const unsigned short* Bb = J.B + (long)batch * J.sBb;

  const unsigned short* gsrc[GPW];
  int ldsdst[GPW];
#pragma unroll
  for (int i = 0; i < GPW; i++) {
    const int c = w + i * 8;
    const bool isA = (c < 16);
    const int cc = isA ? c : c - 16;
    const int roff = cc * 1024 + lane * 16;
    const int L = roff ^ (((roff >> 7) & 7) << 4);
    const int row = L >> 6, colb = L & 63;
    gsrc[i] = (isA ? (Ab + (long)(brow + row) * J.lda)
                   : (Bb + (long)(bcol + row) * J.ldb)) + (colb >> 1);
    ldsdst[i] = (isA ? 0 : ASLOT) + cc * 1024;
  }

  int offA[8], offB[NFRAG];
#pragma unroll
  for (int mi = 0; mi < 8; mi++) {
    const int oa = (wm * 128 + mi * 16 + fr) * 64 + fq * 16;
    offA[mi] = oa ^ (((oa >> 7) & 7) << 4);
  }
#pragma unroll
  for (int ni = 0; ni < NFRAG; ni++) {
    const int ob = (wn * (NFRAG * 16) + ni * 16 + fr) * 64 + fq * 16;
    offB[ni] = ASLOT + (ob ^ (((ob >> 7) & 7) << 4));
  }

  f32x4 acc[8][NFRAG];
#pragma unroll
  for (int mi = 0; mi < 8; mi++)
#pragma unroll
    for (int ni = 0; ni < NFRAG; ni++) acc[mi][ni] = (f32x4){0.f, 0.f, 0.f, 0.f};

  const int NT = J.K >> 5;

#define STAGE(kt) { \
  char* const sb_ = lds + ((kt) & 3) * SLOT; \
  _Pragma("unroll") \
  for (int i_ = 0; i_ < GPW; i_++) \
    gload_lds16(gsrc[i_] + (long)(kt) * 32, sb_ + ldsdst[i_]); }

  STAGE(0);
  STAGE(1);
  waitvm<GPW>();
  __builtin_amdgcn_s_barrier();

  for (int t = 0; t < NT; ++t) {
    const char* sb = lds + (t & 3) * SLOT;
    if (t + 2 < NT) STAGE(t + 2);

    s8v bf[NFRAG], af[4];
#pragma unroll
    for (int ni = 0; ni < NFRAG; ni++) bf[ni] = *(const s8v*)(sb + offB[ni]);
#pragma unroll
    for (int mi = 0; mi < 4; mi++) af[mi] = *(const s8v*)(sb + offA[mi]);
    __builtin_amdgcn_s_setprio(1);
#pragma unroll
    for (int mi = 0; mi < 4; mi++)
#pragma unroll
      for (int ni = 0; ni < NFRAG; ni++)
        acc[mi][ni] = __builtin_amdgcn_mfma_f32_16x16x32_bf16(
            af[mi], bf[ni], acc[mi][ni], 0, 0, 0);
    __builtin_amdgcn_s_setprio(0);
#pragma unroll
    for (int mi = 0; mi < 4; mi++) af[mi] = *(const s8v*)(sb + offA[4 + mi]);
    __builtin_amdgcn_s_setprio(1);
#pragma unroll
    for (int mi = 0; mi < 4; mi++)
#pragma unroll
      for (int ni = 0; ni < NFRAG; ni++)
        acc[4 + mi][ni] = __builtin_amdgcn_mfma_f32_16x16x32_bf16(
            af[mi], bf[ni], acc[4 + mi][ni], 0, 0, 0);
    __builtin_amdgcn_s_setprio(0);

    if (t + 1 < NT) {
      if (t + 2 < NT) waitvm<GPW>();
      else            waitvm<0>();
      __builtin_amdgcn_s_barrier();
    }
  }

  unsigned short* Cb = (unsigned short*)J.C;
  float* Cf = (float*)J.C;
  const long cB = (long)batch * J.sCb;
  const float* maskB = (MODE == 1) ? (J.mask + (long)batch * J.sMb) : nullptr;
  float* sB = (J.sRow != nullptr) ? (J.sRow + batch * 2048) : nullptr;

#pragma unroll
  for (int mi = 0; mi < 8; mi++) {
    const int rbase = brow + wm * 128 + mi * 16 + fq * 4;

    if constexpr (MODE == 1) {
      float rs[4] = {0.f, 0.f, 0.f, 0.f};
#pragma unroll
      for (int ni = 0; ni < NFRAG; ni++) {
        const int col = bcol + wn * (NFRAG * 16) + ni * 16 + fr;
#pragma unroll
        for (int r = 0; r < 4; r++) {
          const int row = rbase + r;
          float v = acc[mi][ni][r] * J.scale + maskB[(long)row * J.ldM + col];
          v = __expf(v);
          Cb[cB + (long)row * J.ldc + col] = f2b(v);
          rs[r] += v;
        }
      }
#pragma unroll
      for (int off = 1; off < 16; off <<= 1) {
#pragma unroll
        for (int r = 0; r < 4; r++) rs[r] += __shfl_xor(rs[r], off, 64);
      }
      if (fr == 0) {
#pragma unroll
        for (int r = 0; r < 4; r++) atomicAdd(&sB[rbase + r], rs[r]);
      }
    } else {  // MODE 2: PV, normalize by 1/sRow
      float inv[4];
#pragma unroll
      for (int r = 0; r < 4; r++) inv[r] = 1.0f / sB[rbase + r];
#pragma unroll
      for (int ni = 0; ni < NFRAG; ni++) {
        const int col = bcol + wn * (NFRAG * 16) + ni * 16 + fr;
#pragma unroll
        for (int r = 0; r < 4; r++) {
          const int row = rbase + r;
          Cf[cB + (long)row * J.ldc + col] = acc[mi][ni][r] * inv[r];
        }
      }
    }
  }
#undef STAGE
}

// zero sRow[8192]
__global__ __launch_bounds__(256) void zeroS(float* sz) {
  sz[blockIdx.x * 256 + threadIdx.x] = 0.f;
}

extern "C" void kernel_launch(void* const* d_in, const int* in_sizes, int n_in,
                              void* d_out, int out_size, void* d_ws, size_t ws_size,
                              hipStream_t stream) {
  const float* q    = (const float*)d_in[0];
  const float* k    = (const float*)d_in[1];
  const float* v    = (const float*)d_in[2];
  const float* mask = (const float*)d_in[3];
  const float* Wq   = (const float*)d_in[4];
  const float* bq   = (const float*)d_in[5];
  const float* Wk   = (const float*)d_in[6];
  const float* bk   = (const float*)d_in[7];
  const float* Wv   = (const float*)d_in[8];
  const float* bv   = (const float*)d_in[9];
  float* out = (float*)d_out;

  const size_t MB = 1ull << 20;
  if (ws_size < 134 * MB) return;
  char* ws = (char*)d_ws;
  unsigned short* qb  = (unsigned short*)(ws + 0 * MB);
  unsigned short* kb  = (unsigned short*)(ws + 16 * MB);
  unsigned short* vT  = (unsigned short*)(ws + 32 * MB);
  float*          sRw = (float*)(ws + 48 * MB);           // 32KB
  unsigned short* Sb  = (unsigned short*)(ws + 80 * MB);  // 32MB

  zeroS<<<32, 256, 0, stream>>>(sRw);

  // QKV fused from raw f32 (768 blocks): q-proj 256 (32 tm x 8 tn),
  // k-proj 256, v-proj transposed 256 (A=Wv M=1024: 4 tm x 16 tn x 4 b).
  JobF fq = { q, Wq, qb, bq, 0, 0, 0, 1024, 1024, 1024, 8, 256, 1 };
  JobF fk = { k, Wk, kb, bk, 0, 0, 0, 1024, 1024, 1024, 8, 256, 1 };
  JobF fv = { Wv, v, vT, bv, 0, 2048L * 1024, 1024L * 2048,
              1024, 1024, 2048, 16, 64, 2 };
  gemmF<<<768, 512, 0, stream>>>(fq, fk, fv, 256, 512);

  // scores -> E = exp(qk/32 + mask), bf16, + row sums. 8x8x4 = 256 blocks.
  Job js = { qb, kb, (void*)Sb, nullptr, mask, sRw,
             2048L * 1024, 2048L * 1024, 2048L * 2048, 2048L * 2048,
             1024, 1024, 2048, 2048, 1024, 8, 64, 0.03125f, 0 };
  gemmJ<4, 1><<<256, 512, 0, stream>>>(js, js, js, 256, 256);

  // PV: out = (E . vT^T) / sRow; 8 tm x 8 tn x 4 = 256 blocks, K=2048.
  Job jp = { Sb, vT, (void*)out, nullptr, nullptr, sRw,
             2048L * 2048, 1024L * 2048, 2048L * 1024, 0,
             2048, 2048, 1024, 0, 2048, 8, 64, 1.0f, 0 };
  gemmJ<2, 2><<<256, 512, 0, stream>>>(jp, jp, jp, 256, 256);
}